// Round 2
// baseline (278.581 us; speedup 1.0000x reference)
//
#include <hip/hip_runtime.h>
#include <math.h>

#define NUM_VARS 64
#define KK       32
#define NUM_CATS 256
#define LL       4
#define EE       16384
#define NN       8192
#define CC       4
#define BB       1024
#define NUM_INPUT 2048           // NUM_VARS * KK
#define TOTAL_ROWS 34816         // NUM_INPUT + LL*NN
#define NP       8               // nodes per block in layer kernel
#define ROOT_CHUNKS 256          // row-chunks in root partial reduce

// ---------------------------------------------------------------------------
// Input layer: nm[v*K + k][b] = input_logp[v][k][inputs[b][v]]
// grid: (B/256, NUM_VARS), block: 256
// ---------------------------------------------------------------------------
__global__ void input_kernel(const int* __restrict__ inputs,
                             const float* __restrict__ input_logp,
                             float* __restrict__ nm) {
    int b = blockIdx.x * 256 + threadIdx.x;
    int v = blockIdx.y;
    int cat = inputs[b * NUM_VARS + v];
    const float* lp = input_logp + ((size_t)v * KK) * NUM_CATS + cat;
    float* dst = nm + (size_t)(v * KK) * BB + b;
#pragma unroll
    for (int k = 0; k < KK; ++k) {
        dst[(size_t)k * BB] = lp[(size_t)k * NUM_CATS];
    }
}

// ---------------------------------------------------------------------------
// Prep: collapse sum_ch_ids -> prod_ids double indirection into direct
// node_mars row indices. pairs[l][n] = {r00,r01,r10,r11, r20,r21,r30,r31}
// grid: L*N/256 blocks.
// ---------------------------------------------------------------------------
__global__ void prep_kernel(const int* __restrict__ prod_ids,    // L x E x 2
                            const int* __restrict__ sum_ch_ids,  // L x N x C
                            int4* __restrict__ pairs)            // L x N x 2
{
    int idx = blockIdx.x * 256 + threadIdx.x;     // 0 .. L*N-1
    int l = idx >> 13;                            // / NN
    const int*  sch  = sum_ch_ids + (size_t)idx * CC;
    const int2* prod = (const int2*)prod_ids + (size_t)l * EE;
    int2 p0 = prod[sch[0]];
    int2 p1 = prod[sch[1]];
    int2 p2 = prod[sch[2]];
    int2 p3 = prod[sch[3]];
    pairs[(size_t)idx * 2]     = make_int4(p0.x, p0.y, p1.x, p1.y);
    pairs[(size_t)idx * 2 + 1] = make_int4(p2.x, p2.y, p3.x, p3.y);
}

__device__ __forceinline__ float lse4(float a, float b, float c, float d) {
    float m = fmaxf(fmaxf(a, b), fmaxf(c, d));
    float s = __expf(a - m) + __expf(b - m) + __expf(c - m) + __expf(d - m);
    return m + __logf(s);
}

// ---------------------------------------------------------------------------
// One sum layer. Thread t handles 4 consecutive batch cols (float4).
// Indices prefetched for all NP nodes (wave-uniform -> SGPRs), then 8
// independent row loads per node, fully unrolled for MLP.
// ---------------------------------------------------------------------------
__global__ __launch_bounds__(256, 4)
void layer_kernel(const float4* __restrict__ nm4,
                  float4* __restrict__ out4,
                  const int4* __restrict__ pairs,  // N x 2
                  const float4* __restrict__ slw)  // N x 4 log-weights
{
    int t = threadIdx.x;                 // 0..255 -> 4 batch cols each
    int n0 = blockIdx.x * NP;

    int4  pa[NP], pb[NP];
    float4 w[NP];
#pragma unroll
    for (int i = 0; i < NP; ++i) {
        pa[i] = pairs[(size_t)(n0 + i) * 2];
        pb[i] = pairs[(size_t)(n0 + i) * 2 + 1];
        w[i]  = slw[n0 + i];
    }

#pragma unroll
    for (int i = 0; i < NP; ++i) {
        float4 a0 = nm4[(size_t)pa[i].x * (BB / 4) + t];
        float4 b0 = nm4[(size_t)pa[i].y * (BB / 4) + t];
        float4 a1 = nm4[(size_t)pa[i].z * (BB / 4) + t];
        float4 b1 = nm4[(size_t)pa[i].w * (BB / 4) + t];
        float4 a2 = nm4[(size_t)pb[i].x * (BB / 4) + t];
        float4 b2 = nm4[(size_t)pb[i].y * (BB / 4) + t];
        float4 a3 = nm4[(size_t)pb[i].z * (BB / 4) + t];
        float4 b3 = nm4[(size_t)pb[i].w * (BB / 4) + t];

        float4 r;
        r.x = lse4(w[i].x + a0.x + b0.x, w[i].y + a1.x + b1.x,
                   w[i].z + a2.x + b2.x, w[i].w + a3.x + b3.x);
        r.y = lse4(w[i].x + a0.y + b0.y, w[i].y + a1.y + b1.y,
                   w[i].z + a2.y + b2.y, w[i].w + a3.y + b3.y);
        r.z = lse4(w[i].x + a0.z + b0.z, w[i].y + a1.z + b1.z,
                   w[i].z + a2.z + b2.z, w[i].w + a3.z + b3.z);
        r.w = lse4(w[i].x + a0.w + b0.w, w[i].y + a1.w + b1.w,
                   w[i].z + a2.w + b2.w, w[i].w + a3.w + b3.w);

        out4[(size_t)(n0 + i) * (BB / 4) + t] = r;
    }
}

// ---------------------------------------------------------------------------
// Root reduce, stage 1: each block (1024 threads = one per batch col)
// online-logsumexps NN/ROOT_CHUNKS rows with 4 split accumulators.
// ---------------------------------------------------------------------------
__global__ void root_partial(const float* __restrict__ last,  // N x B
                             const float* __restrict__ rlw,   // N
                             float2* __restrict__ part) {
    int b = threadIdx.x;                       // 0..1023
    int chunk = blockIdx.x;                    // 0..ROOT_CHUNKS-1
    const int rows = NN / ROOT_CHUNKS;         // 32
    int n0 = chunk * rows;
    float m0 = -INFINITY, m1 = -INFINITY, m2 = -INFINITY, m3 = -INFINITY;
    float s0 = 0.f, s1 = 0.f, s2 = 0.f, s3 = 0.f;
#pragma unroll
    for (int i = 0; i < rows; i += 4) {
        float v0 = rlw[n0 + i + 0] + last[(size_t)(n0 + i + 0) * BB + b];
        float v1 = rlw[n0 + i + 1] + last[(size_t)(n0 + i + 1) * BB + b];
        float v2 = rlw[n0 + i + 2] + last[(size_t)(n0 + i + 2) * BB + b];
        float v3 = rlw[n0 + i + 3] + last[(size_t)(n0 + i + 3) * BB + b];
        float t0 = fmaxf(m0, v0); s0 = s0 * __expf(m0 - t0) + __expf(v0 - t0); m0 = t0;
        float t1 = fmaxf(m1, v1); s1 = s1 * __expf(m1 - t1) + __expf(v1 - t1); m1 = t1;
        float t2 = fmaxf(m2, v2); s2 = s2 * __expf(m2 - t2) + __expf(v2 - t2); m2 = t2;
        float t3 = fmaxf(m3, v3); s3 = s3 * __expf(m3 - t3) + __expf(v3 - t3); m3 = t3;
    }
    float m = fmaxf(fmaxf(m0, m1), fmaxf(m2, m3));
    float s = s0 * __expf(m0 - m) + s1 * __expf(m1 - m) +
              s2 * __expf(m2 - m) + s3 * __expf(m3 - m);
    part[(size_t)chunk * BB + b] = make_float2(m, s);
}

// ---------------------------------------------------------------------------
// Root reduce, stage 2: combine ROOT_CHUNKS partials per batch col.
// ---------------------------------------------------------------------------
__global__ void root_final(const float2* __restrict__ part,
                           float* __restrict__ out) {
    int b = blockIdx.x * 256 + threadIdx.x;
    float m = -INFINITY;
#pragma unroll 8
    for (int c = 0; c < ROOT_CHUNKS; ++c) m = fmaxf(m, part[(size_t)c * BB + b].x);
    float s = 0.f;
#pragma unroll 8
    for (int c = 0; c < ROOT_CHUNKS; ++c) {
        float2 p = part[(size_t)c * BB + b];
        s += p.y * __expf(p.x - m);
    }
    out[b] = m + __logf(s);
}

extern "C" void kernel_launch(void* const* d_in, const int* in_sizes, int n_in,
                              void* d_out, int out_size, void* d_ws, size_t ws_size,
                              hipStream_t stream) {
    const int*   inputs      = (const int*)d_in[0];
    const float* input_logp  = (const float*)d_in[1];
    const int*   prod_ids    = (const int*)d_in[2];
    const int*   sum_ch_ids  = (const int*)d_in[3];
    const float* sum_logw    = (const float*)d_in[4];
    const float* root_logw   = (const float*)d_in[5];
    float* out = (float*)d_out;

    float*  nm    = (float*)d_ws;                          // [34816][1024] f32
    int4*   pairs = (int4*)(nm + (size_t)TOTAL_ROWS * BB); // [L*N][2] int4
    float2* part  = (float2*)(pairs + (size_t)LL * NN * 2);// [256][1024] float2

    input_kernel<<<dim3(BB / 256, NUM_VARS), 256, 0, stream>>>(inputs, input_logp, nm);
    prep_kernel<<<(LL * NN) / 256, 256, 0, stream>>>(prod_ids, sum_ch_ids, pairs);

    for (int l = 0; l < LL; ++l) {
        const float* slw  = sum_logw + (size_t)l * NN * CC;
        float* outl = nm + (size_t)(NUM_INPUT + l * NN) * BB;
        layer_kernel<<<NN / NP, 256, 0, stream>>>(
            (const float4*)nm, (float4*)outl,
            pairs + (size_t)l * NN * 2, (const float4*)slw);
    }

    const float* last = nm + (size_t)(NUM_INPUT + (LL - 1) * NN) * BB;
    root_partial<<<ROOT_CHUNKS, 1024, 0, stream>>>(last, root_logw, part);
    root_final<<<BB / 256, 256, 0, stream>>>(part, out);
}

// Round 3
// 160.239 us; speedup vs baseline: 1.7385x; 1.7385x over previous
//
#include <hip/hip_runtime.h>
#include <math.h>

#define NUM_VARS 64
#define KK       32
#define NUM_CATS 256
#define LL       4
#define EE       16384
#define NN       8192
#define CC       4
#define BB       1024
#define NUM_INPUT 2048             // NUM_VARS * KK
#define ROWS_LDS  26624            // NUM_INPUT + 3*NN (last layer not stored)
#define THREADS   512
// dynamic LDS: node values + 8-wave reduce scratch (m,s) + cats
#define LDS_FLOATS (ROWS_LDS + 32 + 64)
#define LDS_BYTES  (LDS_FLOATS * 4)

// ---------------------------------------------------------------------------
// Prep: collapse sum_ch_ids -> prod_ids double indirection into u16 row ids,
// fold root_logw into layer-3 weights. grid: L*N/256.
// recA[idx] = 8 x u16 child-row ids (int4), recB[idx] = 4 x f32 weights.
// ---------------------------------------------------------------------------
__global__ void prep_kernel(const int* __restrict__ prod_ids,    // L x E x 2
                            const int* __restrict__ sum_ch_ids,  // L x N x C
                            const float* __restrict__ sum_logw,  // L x N x C
                            const float* __restrict__ root_logw, // N
                            int4* __restrict__ recA,
                            float4* __restrict__ recB)
{
    int idx = blockIdx.x * 256 + threadIdx.x;     // 0 .. L*N-1
    int l = idx >> 13;
    int n = idx & (NN - 1);
    const int*  sch  = sum_ch_ids + (size_t)idx * CC;
    const int2* prod = (const int2*)prod_ids + (size_t)l * EE;
    int2 p0 = prod[sch[0]];
    int2 p1 = prod[sch[1]];
    int2 p2 = prod[sch[2]];
    int2 p3 = prod[sch[3]];
    int4 a;
    a.x = (p0.x & 0xffff) | (p0.y << 16);
    a.y = (p1.x & 0xffff) | (p1.y << 16);
    a.z = (p2.x & 0xffff) | (p2.y << 16);
    a.w = (p3.x & 0xffff) | (p3.y << 16);
    recA[idx] = a;

    const float* w = sum_logw + (size_t)idx * CC;
    float r = (l == 3) ? root_logw[n] : 0.0f;
    recB[idx] = make_float4(w[0] + r, w[1] + r, w[2] + r, w[3] + r);
}

__device__ __forceinline__ float lse4(float a, float b, float c, float d) {
    float m = fmaxf(fmaxf(a, b), fmaxf(c, d));
    float s = __expf(a - m) + __expf(b - m) + __expf(c - m) + __expf(d - m);
    return m + __logf(s);
}

// ---------------------------------------------------------------------------
// Mega-kernel: one block = one batch column. Whole column's node values live
// in LDS; layers computed in-place; root lse fused (root_logw pre-folded).
// ---------------------------------------------------------------------------
__global__ __launch_bounds__(THREADS, 1)
void circuit_kernel(const int* __restrict__ inputs,          // B x NUM_VARS
                    const float* __restrict__ input_logp,    // V x K x CATS
                    const int4* __restrict__ recA,           // L*N
                    const float4* __restrict__ recB,         // L*N
                    float* __restrict__ out)                 // B
{
    extern __shared__ float lds[];
    float* red  = lds + ROWS_LDS;          // 32 floats (8 waves x m,s)
    int*   cats = (int*)(lds + ROWS_LDS + 32);

    int b = blockIdx.x;
    int t = threadIdx.x;

    if (t < NUM_VARS) cats[t] = inputs[b * NUM_VARS + t];
    __syncthreads();

    // ---- input layer: lds[v*K + k] = input_logp[(v*K+k)*CATS + cat[v]]
#pragma unroll
    for (int i = 0; i < NUM_INPUT / THREADS; ++i) {
        int idx = t + i * THREADS;
        int v = idx >> 5;
        lds[idx] = input_logp[(size_t)idx * NUM_CATS + cats[v]];
    }
    __syncthreads();

    // ---- layers 0..2: store into LDS
    for (int l = 0; l < 3; ++l) {
        const int4*   ra = recA + (size_t)l * NN;
        const float4* rb = recB + (size_t)l * NN;
        float* dst = lds + NUM_INPUT + l * NN;
#pragma unroll 4
        for (int i = 0; i < NN / THREADS; ++i) {
            int n = t + i * THREADS;
            int4 r = ra[n];
            float4 w = rb[n];
            float a0 = lds[r.x & 0xffff] + lds[(r.x >> 16) & 0xffff];
            float a1 = lds[r.y & 0xffff] + lds[(r.y >> 16) & 0xffff];
            float a2 = lds[r.z & 0xffff] + lds[(r.z >> 16) & 0xffff];
            float a3 = lds[r.w & 0xffff] + lds[(r.w >> 16) & 0xffff];
            dst[n] = lse4(w.x + a0, w.y + a1, w.z + a2, w.w + a3);
        }
        __syncthreads();
    }

    // ---- layer 3 + root accumulate (root_logw already folded into weights)
    {
        const int4*   ra = recA + (size_t)3 * NN;
        const float4* rb = recB + (size_t)3 * NN;
        float m = -INFINITY, s = 0.0f;
#pragma unroll 4
        for (int i = 0; i < NN / THREADS; ++i) {
            int n = t + i * THREADS;
            int4 r = ra[n];
            float4 w = rb[n];
            float a0 = lds[r.x & 0xffff] + lds[(r.x >> 16) & 0xffff];
            float a1 = lds[r.y & 0xffff] + lds[(r.y >> 16) & 0xffff];
            float a2 = lds[r.z & 0xffff] + lds[(r.z >> 16) & 0xffff];
            float a3 = lds[r.w & 0xffff] + lds[(r.w >> 16) & 0xffff];
            float v = lse4(w.x + a0, w.y + a1, w.z + a2, w.w + a3);
            float nm_ = fmaxf(m, v);
            s = s * __expf(m - nm_) + __expf(v - nm_);
            m = nm_;
        }
        // wave reduce (64 lanes)
#pragma unroll
        for (int off = 32; off >= 1; off >>= 1) {
            float om = __shfl_xor(m, off);
            float os = __shfl_xor(s, off);
            float nm_ = fmaxf(m, om);
            s = s * __expf(m - nm_) + os * __expf(om - nm_);
            m = nm_;
        }
        int wid = t >> 6;
        if ((t & 63) == 0) { red[wid * 2] = m; red[wid * 2 + 1] = s; }
        __syncthreads();
        if (t == 0) {
            float M = -INFINITY;
#pragma unroll
            for (int wv = 0; wv < THREADS / 64; ++wv) M = fmaxf(M, red[wv * 2]);
            float S = 0.0f;
#pragma unroll
            for (int wv = 0; wv < THREADS / 64; ++wv)
                S += red[wv * 2 + 1] * __expf(red[wv * 2] - M);
            out[b] = M + __logf(S);
        }
    }
}

extern "C" void kernel_launch(void* const* d_in, const int* in_sizes, int n_in,
                              void* d_out, int out_size, void* d_ws, size_t ws_size,
                              hipStream_t stream) {
    const int*   inputs      = (const int*)d_in[0];
    const float* input_logp  = (const float*)d_in[1];
    const int*   prod_ids    = (const int*)d_in[2];
    const int*   sum_ch_ids  = (const int*)d_in[3];
    const float* sum_logw    = (const float*)d_in[4];
    const float* root_logw   = (const float*)d_in[5];
    float* out = (float*)d_out;

    int4*   recA = (int4*)d_ws;                     // [L*N] 16B
    float4* recB = (float4*)(recA + (size_t)LL * NN); // [L*N] 16B

    // allow >64KB dynamic LDS (idempotent; safe under graph capture)
    static bool attr_done = false;
    if (!attr_done) {
        hipFuncSetAttribute((const void*)circuit_kernel,
                            hipFuncAttributeMaxDynamicSharedMemorySize, LDS_BYTES);
        attr_done = true;
    }

    prep_kernel<<<(LL * NN) / 256, 256, 0, stream>>>(
        prod_ids, sum_ch_ids, sum_logw, root_logw, recA, recB);

    circuit_kernel<<<BB, THREADS, LDS_BYTES, stream>>>(
        inputs, input_logp, recA, recB, out);
}

// Round 5
// 153.919 us; speedup vs baseline: 1.8099x; 1.0411x over previous
//
#include <hip/hip_runtime.h>
#include <math.h>

#define NUM_VARS 64
#define KK       32
#define NUM_CATS 256
#define LL       4
#define EE       16384
#define NN       8192
#define CC       4
#define BB       1024
#define NUM_INPUT 2048             // NUM_VARS * KK
#define ROWS_LDS  26624            // NUM_INPUT + 3*NN (last layer not stored)
#define THREADS   1024
// dynamic LDS: node values + 16-wave reduce scratch (m,s) + cats
#define LDS_FLOATS (ROWS_LDS + 32 + 64)
#define LDS_BYTES  (LDS_FLOATS * 4)

#define LOG2E 1.4426950408889634f
#define LN2   0.6931471805599453f

#if __has_builtin(__builtin_amdgcn_exp2f)
#define EXP2(x) __builtin_amdgcn_exp2f(x)
#else
#define EXP2(x) exp2f(x)
#endif
#if __has_builtin(__builtin_amdgcn_logf)
#define LOG2(x) __builtin_amdgcn_logf(x)
#else
#define LOG2(x) log2f(x)
#endif

// ---------------------------------------------------------------------------
// Prep: collapse sum_ch_ids -> prod_ids double indirection into 8 direct LDS
// BYTE offsets per node (u32, row*4), weights pre-scaled to base-2 domain,
// root_logw folded into layer-3 weights. grid: L*N/256.
// ---------------------------------------------------------------------------
__global__ void prep_kernel(const int* __restrict__ prod_ids,    // L x E x 2
                            const int* __restrict__ sum_ch_ids,  // L x N x C
                            const float* __restrict__ sum_logw,  // L x N x C
                            const float* __restrict__ root_logw, // N
                            int4* __restrict__ recA,             // L*N x 2
                            float4* __restrict__ recB)           // L*N
{
    int idx = blockIdx.x * 256 + threadIdx.x;     // 0 .. L*N-1
    int l = idx >> 13;
    int n = idx & (NN - 1);
    const int*  sch  = sum_ch_ids + (size_t)idx * CC;
    const int2* prod = (const int2*)prod_ids + (size_t)l * EE;
    int2 p0 = prod[sch[0]];
    int2 p1 = prod[sch[1]];
    int2 p2 = prod[sch[2]];
    int2 p3 = prod[sch[3]];
    recA[(size_t)idx * 2]     = make_int4(p0.x << 2, p0.y << 2, p1.x << 2, p1.y << 2);
    recA[(size_t)idx * 2 + 1] = make_int4(p2.x << 2, p2.y << 2, p3.x << 2, p3.y << 2);

    const float* w = sum_logw + (size_t)idx * CC;
    float r = (l == 3) ? root_logw[n] : 0.0f;
    recB[idx] = make_float4((w[0] + r) * LOG2E, (w[1] + r) * LOG2E,
                            (w[2] + r) * LOG2E, (w[3] + r) * LOG2E);
}

// base-2 logsumexp of 4
__device__ __forceinline__ float lse4_2(float a, float b, float c, float d) {
    float m = fmaxf(fmaxf(a, b), fmaxf(c, d));
    float s = EXP2(a - m) + EXP2(b - m) + EXP2(c - m) + EXP2(d - m);
    return m + LOG2(s);
}

__device__ __forceinline__ float ldsb(const float* lds, int byteoff) {
    return *(const float*)((const char*)lds + byteoff);
}

// ---------------------------------------------------------------------------
// Mega-kernel: one block = one batch column; whole column resident in LDS.
// All values in base-2 log domain. Root lse fused (root_logw pre-folded).
// ---------------------------------------------------------------------------
__global__ __launch_bounds__(THREADS, 1)
void circuit_kernel(const int* __restrict__ inputs,          // B x NUM_VARS
                    const float* __restrict__ input_logp,    // V x K x CATS
                    const int4* __restrict__ recA,           // L*N x 2
                    const float4* __restrict__ recB,         // L*N
                    float* __restrict__ out)                 // B
{
    extern __shared__ float lds[];
    float* red  = lds + ROWS_LDS;          // 32 floats (16 waves x m,s)
    int*   cats = (int*)(lds + ROWS_LDS + 32);

    int b = blockIdx.x;
    int t = threadIdx.x;

    if (t < NUM_VARS) cats[t] = inputs[b * NUM_VARS + t];
    __syncthreads();

    // ---- input layer: lds[v*K + k] = log2e * input_logp[(v*K+k)*CATS + cat[v]]
#pragma unroll
    for (int i = 0; i < NUM_INPUT / THREADS; ++i) {
        int idx = t + i * THREADS;
        int v = idx >> 5;
        lds[idx] = input_logp[(size_t)idx * NUM_CATS + cats[v]] * LOG2E;
    }
    __syncthreads();

    // ---- layers 0..2: store into LDS
    for (int l = 0; l < 3; ++l) {
        const int4*   ra = recA + (size_t)l * NN * 2;
        const float4* rb = recB + (size_t)l * NN;
        float* dst = lds + NUM_INPUT + l * NN;
#pragma unroll 4
        for (int i = 0; i < NN / THREADS; ++i) {
            int n = t + i * THREADS;
            int4 r0 = ra[(size_t)n * 2];
            int4 r1 = ra[(size_t)n * 2 + 1];
            float4 w = rb[n];
            float a0 = ldsb(lds, r0.x) + ldsb(lds, r0.y);
            float a1 = ldsb(lds, r0.z) + ldsb(lds, r0.w);
            float a2 = ldsb(lds, r1.x) + ldsb(lds, r1.y);
            float a3 = ldsb(lds, r1.z) + ldsb(lds, r1.w);
            dst[n] = lse4_2(w.x + a0, w.y + a1, w.z + a2, w.w + a3);
        }
        __syncthreads();
    }

    // ---- layer 3 + root accumulate (root_logw already folded into weights)
    {
        const int4*   ra = recA + (size_t)3 * NN * 2;
        const float4* rb = recB + (size_t)3 * NN;
        float m = -INFINITY, s = 0.0f;
#pragma unroll 4
        for (int i = 0; i < NN / THREADS; ++i) {
            int n = t + i * THREADS;
            int4 r0 = ra[(size_t)n * 2];
            int4 r1 = ra[(size_t)n * 2 + 1];
            float4 w = rb[n];
            float a0 = ldsb(lds, r0.x) + ldsb(lds, r0.y);
            float a1 = ldsb(lds, r0.z) + ldsb(lds, r0.w);
            float a2 = ldsb(lds, r1.x) + ldsb(lds, r1.y);
            float a3 = ldsb(lds, r1.z) + ldsb(lds, r1.w);
            float v = lse4_2(w.x + a0, w.y + a1, w.z + a2, w.w + a3);
            float nm_ = fmaxf(m, v);
            s = s * EXP2(m - nm_) + EXP2(v - nm_);
            m = nm_;
        }
        // wave reduce (64 lanes)
#pragma unroll
        for (int off = 32; off >= 1; off >>= 1) {
            float om = __shfl_xor(m, off);
            float os = __shfl_xor(s, off);
            float nm_ = fmaxf(m, om);
            s = s * EXP2(m - nm_) + os * EXP2(om - nm_);
            m = nm_;
        }
        int wid = t >> 6;
        if ((t & 63) == 0) { red[wid * 2] = m; red[wid * 2 + 1] = s; }
        __syncthreads();
        if (t == 0) {
            float M = -INFINITY;
#pragma unroll
            for (int wv = 0; wv < THREADS / 64; ++wv) M = fmaxf(M, red[wv * 2]);
            float S = 0.0f;
#pragma unroll
            for (int wv = 0; wv < THREADS / 64; ++wv)
                S += red[wv * 2 + 1] * EXP2(red[wv * 2] - M);
            out[b] = (M + LOG2(S)) * LN2;
        }
    }
}

extern "C" void kernel_launch(void* const* d_in, const int* in_sizes, int n_in,
                              void* d_out, int out_size, void* d_ws, size_t ws_size,
                              hipStream_t stream) {
    const int*   inputs      = (const int*)d_in[0];
    const float* input_logp  = (const float*)d_in[1];
    const int*   prod_ids    = (const int*)d_in[2];
    const int*   sum_ch_ids  = (const int*)d_in[3];
    const float* sum_logw    = (const float*)d_in[4];
    const float* root_logw   = (const float*)d_in[5];
    float* out = (float*)d_out;

    int4*   recA = (int4*)d_ws;                       // [L*N][2] int4
    float4* recB = (float4*)(recA + (size_t)LL * NN * 2); // [L*N] float4

    static bool attr_done = false;
    if (!attr_done) {
        hipFuncSetAttribute((const void*)circuit_kernel,
                            hipFuncAttributeMaxDynamicSharedMemorySize, LDS_BYTES);
        attr_done = true;
    }

    prep_kernel<<<(LL * NN) / 256, 256, 0, stream>>>(
        prod_ids, sum_ch_ids, sum_logw, root_logw, recA, recB);

    circuit_kernel<<<BB, THREADS, LDS_BYTES, stream>>>(
        inputs, input_logp, recA, recB, out);
}

// Round 6
// 126.458 us; speedup vs baseline: 2.2030x; 1.2172x over previous
//
#include <hip/hip_runtime.h>
#include <hip/hip_fp16.h>
#include <math.h>

#define NUM_VARS 64
#define KK       32
#define NUM_CATS 256
#define LL       4
#define EE       16384
#define NN       8192
#define CC       4
#define BB       1024
#define NUM_INPUT 2048             // NUM_VARS * KK
#define ROWS_LDS  26624            // NUM_INPUT + 3*NN (last layer not stored)
#define THREADS   1024
// LDS: 26624 rows x __half2 (4B) + 64 f32 reduce scratch + 128 int cats
#define LDS_FLOATS (ROWS_LDS + 64 + 128)
#define LDS_BYTES  (LDS_FLOATS * 4)

#define LOG2E 1.4426950408889634f
#define LN2   0.6931471805599453f

#if __has_builtin(__builtin_amdgcn_exp2f)
#define EXP2(x) __builtin_amdgcn_exp2f(x)
#else
#define EXP2(x) exp2f(x)
#endif
#if __has_builtin(__builtin_amdgcn_logf)
#define LOG2(x) __builtin_amdgcn_logf(x)
#else
#define LOG2(x) log2f(x)
#endif

// Per-layer magnitude biases (log2 domain). Stored row = true - BIAS[layer].
// All bias algebra is folded into prep-computed weights; kernel never sees it.
#define B_IN  (-9.0f)
#define B_L0  (-19.0f)
#define B_L1  (-39.0f)
#define B_L2  (-79.0f)

__device__ __forceinline__ float child_bias(int row) {
    // layer of a child row: input / L0 / L1 / L2 (layer-3 rows are never children)
    if (row < NUM_INPUT) return B_IN;
    int l = (row - NUM_INPUT) >> 13;
    return l == 0 ? B_L0 : (l == 1 ? B_L1 : B_L2);
}

// ---------------------------------------------------------------------------
// Prep: collapse sum_ch_ids -> prod_ids into 8 LDS byte offsets per node;
// weights -> base-2 domain with child/node biases and root_logw folded in.
// grid: L*N/256.
// ---------------------------------------------------------------------------
__global__ void prep_kernel(const int* __restrict__ prod_ids,    // L x E x 2
                            const int* __restrict__ sum_ch_ids,  // L x N x C
                            const float* __restrict__ sum_logw,  // L x N x C
                            const float* __restrict__ root_logw, // N
                            int4* __restrict__ recA,             // L*N x 2
                            float4* __restrict__ recB)           // L*N
{
    int idx = blockIdx.x * 256 + threadIdx.x;     // 0 .. L*N-1
    int l = idx >> 13;
    int n = idx & (NN - 1);
    const int*  sch  = sum_ch_ids + (size_t)idx * CC;
    const int2* prod = (const int2*)prod_ids + (size_t)l * EE;
    int2 p0 = prod[sch[0]];
    int2 p1 = prod[sch[1]];
    int2 p2 = prod[sch[2]];
    int2 p3 = prod[sch[3]];
    recA[(size_t)idx * 2]     = make_int4(p0.x << 2, p0.y << 2, p1.x << 2, p1.y << 2);
    recA[(size_t)idx * 2 + 1] = make_int4(p2.x << 2, p2.y << 2, p3.x << 2, p3.y << 2);

    const float nodeB[4] = {B_L0, B_L1, B_L2, 0.0f};
    float r = (l == 3) ? root_logw[n] : 0.0f;
    const float* w = sum_logw + (size_t)idx * CC;
    float4 wb;
    wb.x = (w[0] + r) * LOG2E + child_bias(p0.x) + child_bias(p0.y) - nodeB[l];
    wb.y = (w[1] + r) * LOG2E + child_bias(p1.x) + child_bias(p1.y) - nodeB[l];
    wb.z = (w[2] + r) * LOG2E + child_bias(p2.x) + child_bias(p2.y) - nodeB[l];
    wb.w = (w[3] + r) * LOG2E + child_bias(p3.x) + child_bias(p3.y) - nodeB[l];
    recB[idx] = wb;
}

// base-2 logsumexp of 4
__device__ __forceinline__ float lse4_2(float a, float b, float c, float d) {
    float m = fmaxf(fmaxf(a, b), fmaxf(c, d));
    float s = EXP2(a - m) + EXP2(b - m) + EXP2(c - m) + EXP2(d - m);
    return m + LOG2(s);
}

// read a row (__half2 = 2 batch columns) by byte offset, unpack to f32
__device__ __forceinline__ float2 ldsh2(const float* lds, int byteoff) {
    __half2 h = *(const __half2*)((const char*)lds + byteoff);
    return __half22float2(h);
}

// ---------------------------------------------------------------------------
// Mega-kernel: one block = TWO batch columns packed as __half2 per row.
// Whole column-pair resident in LDS; compute in f32; base-2 log domain with
// per-layer bias folding (all in prep). Root lse fused.
// ---------------------------------------------------------------------------
__global__ __launch_bounds__(THREADS, 1)
void circuit_kernel(const int* __restrict__ inputs,          // B x NUM_VARS
                    const float* __restrict__ input_logp,    // V x K x CATS
                    const int4* __restrict__ recA,           // L*N x 2
                    const float4* __restrict__ recB,         // L*N
                    float* __restrict__ out)                 // B
{
    extern __shared__ float lds[];
    float* red  = lds + ROWS_LDS;              // 64 floats (16 waves x 4)
    int*   cats = (int*)(lds + ROWS_LDS + 64); // 128 ints (2 cols x 64 vars)
    __half2* rows = (__half2*)lds;

    int b2 = blockIdx.x * 2;                   // first of the 2 batch columns
    int t = threadIdx.x;

    if (t < 128) {
        int col = t >> 6, v = t & 63;
        cats[t] = inputs[(b2 + col) * NUM_VARS + v];
    }
    __syncthreads();

    // ---- input layer: rows[idx] = half2(log2e*logp[idx][catA]-B, ...catB...)
#pragma unroll
    for (int i = 0; i < NUM_INPUT / THREADS; ++i) {
        int idx = t + i * THREADS;
        int v = idx >> 5;
        const float* base = input_logp + (size_t)idx * NUM_CATS;
        float fa = fmaf(base[cats[v]],      LOG2E, -B_IN);
        float fb = fmaf(base[cats[64 + v]], LOG2E, -B_IN);
        rows[idx] = __floats2half2_rn(fa, fb);
    }
    __syncthreads();

    // ---- layers 0..2: store into LDS
    for (int l = 0; l < 3; ++l) {
        const int4*   ra = recA + (size_t)l * NN * 2;
        const float4* rb = recB + (size_t)l * NN;
        __half2* dst = rows + NUM_INPUT + l * NN;
#pragma unroll
        for (int i = 0; i < NN / THREADS; ++i) {
            int n = t + i * THREADS;
            int4 r0 = ra[(size_t)n * 2];
            int4 r1 = ra[(size_t)n * 2 + 1];
            float4 w = rb[n];
            float2 c0 = ldsh2(lds, r0.x), d0 = ldsh2(lds, r0.y);
            float2 c1 = ldsh2(lds, r0.z), d1 = ldsh2(lds, r0.w);
            float2 c2 = ldsh2(lds, r1.x), d2 = ldsh2(lds, r1.y);
            float2 c3 = ldsh2(lds, r1.z), d3 = ldsh2(lds, r1.w);
            float xA = lse4_2(w.x + c0.x + d0.x, w.y + c1.x + d1.x,
                              w.z + c2.x + d2.x, w.w + c3.x + d3.x);
            float xB = lse4_2(w.x + c0.y + d0.y, w.y + c1.y + d1.y,
                              w.z + c2.y + d2.y, w.w + c3.y + d3.y);
            dst[n] = __floats2half2_rn(xA, xB);
        }
        __syncthreads();
    }

    // ---- layer 3 + root accumulate (root_logw folded; node bias 0 -> true)
    {
        const int4*   ra = recA + (size_t)3 * NN * 2;
        const float4* rb = recB + (size_t)3 * NN;
        float mA = -INFINITY, sA = 0.0f, mB = -INFINITY, sB = 0.0f;
#pragma unroll
        for (int i = 0; i < NN / THREADS; ++i) {
            int n = t + i * THREADS;
            int4 r0 = ra[(size_t)n * 2];
            int4 r1 = ra[(size_t)n * 2 + 1];
            float4 w = rb[n];
            float2 c0 = ldsh2(lds, r0.x), d0 = ldsh2(lds, r0.y);
            float2 c1 = ldsh2(lds, r0.z), d1 = ldsh2(lds, r0.w);
            float2 c2 = ldsh2(lds, r1.x), d2 = ldsh2(lds, r1.y);
            float2 c3 = ldsh2(lds, r1.z), d3 = ldsh2(lds, r1.w);
            float vA = lse4_2(w.x + c0.x + d0.x, w.y + c1.x + d1.x,
                              w.z + c2.x + d2.x, w.w + c3.x + d3.x);
            float vB = lse4_2(w.x + c0.y + d0.y, w.y + c1.y + d1.y,
                              w.z + c2.y + d2.y, w.w + c3.y + d3.y);
            float tA = fmaxf(mA, vA);
            sA = sA * EXP2(mA - tA) + EXP2(vA - tA); mA = tA;
            float tB = fmaxf(mB, vB);
            sB = sB * EXP2(mB - tB) + EXP2(vB - tB); mB = tB;
        }
        // wave reduce (64 lanes), both columns
#pragma unroll
        for (int off = 32; off >= 1; off >>= 1) {
            float omA = __shfl_xor(mA, off), osA = __shfl_xor(sA, off);
            float tA = fmaxf(mA, omA);
            sA = sA * EXP2(mA - tA) + osA * EXP2(omA - tA); mA = tA;
            float omB = __shfl_xor(mB, off), osB = __shfl_xor(sB, off);
            float tB = fmaxf(mB, omB);
            sB = sB * EXP2(mB - tB) + osB * EXP2(omB - tB); mB = tB;
        }
        int wid = t >> 6;
        if ((t & 63) == 0) {
            red[wid * 4]     = mA; red[wid * 4 + 1] = sA;
            red[wid * 4 + 2] = mB; red[wid * 4 + 3] = sB;
        }
        __syncthreads();
        if (t == 0) {
            float MA = -INFINITY, MB = -INFINITY;
#pragma unroll
            for (int wv = 0; wv < THREADS / 64; ++wv) {
                MA = fmaxf(MA, red[wv * 4]);
                MB = fmaxf(MB, red[wv * 4 + 2]);
            }
            float SA = 0.0f, SB = 0.0f;
#pragma unroll
            for (int wv = 0; wv < THREADS / 64; ++wv) {
                SA += red[wv * 4 + 1] * EXP2(red[wv * 4]     - MA);
                SB += red[wv * 4 + 3] * EXP2(red[wv * 4 + 2] - MB);
            }
            out[b2]     = (MA + LOG2(SA)) * LN2;
            out[b2 + 1] = (MB + LOG2(SB)) * LN2;
        }
    }
}

extern "C" void kernel_launch(void* const* d_in, const int* in_sizes, int n_in,
                              void* d_out, int out_size, void* d_ws, size_t ws_size,
                              hipStream_t stream) {
    const int*   inputs      = (const int*)d_in[0];
    const float* input_logp  = (const float*)d_in[1];
    const int*   prod_ids    = (const int*)d_in[2];
    const int*   sum_ch_ids  = (const int*)d_in[3];
    const float* sum_logw    = (const float*)d_in[4];
    const float* root_logw   = (const float*)d_in[5];
    float* out = (float*)d_out;

    int4*   recA = (int4*)d_ws;                           // [L*N][2] int4
    float4* recB = (float4*)(recA + (size_t)LL * NN * 2); // [L*N] float4

    static bool attr_done = false;
    if (!attr_done) {
        hipFuncSetAttribute((const void*)circuit_kernel,
                            hipFuncAttributeMaxDynamicSharedMemorySize, LDS_BYTES);
        attr_done = true;
    }

    prep_kernel<<<(LL * NN) / 256, 256, 0, stream>>>(
        prod_ids, sum_ch_ids, sum_logw, root_logw, recA, recB);

    circuit_kernel<<<BB / 2, THREADS, LDS_BYTES, stream>>>(
        inputs, input_logp, recA, recB, out);
}